// Round 3
// baseline (192.649 us; speedup 1.0000x reference)
//
#include <hip/hip_runtime.h>

#define N_NODES 50000
#define E_EDGES 800000
#define CAP     64          // max in-degree capacity; Poisson(16) max over 50k nodes ~ 40

typedef __attribute__((ext_vector_type(8))) short short8;
typedef __attribute__((ext_vector_type(4))) float floatx4;

// float -> bf16 bits, round-to-nearest-even
__device__ __forceinline__ short f2bf(float x) {
    union { float f; unsigned u; } v; v.f = x;
    unsigned r = v.u + 0x7FFFu + ((v.u >> 16) & 1u);
    return (short)(r >> 16);
}

// Kernel A: per-node LayerNorm+ReLU -> h; out = bias + h @ root
__global__ __launch_bounds__(256) void node_kernel(
    const float* __restrict__ x, const float* __restrict__ gamma,
    const float* __restrict__ beta, const float* __restrict__ root,
    const float* __restrict__ bias, float* __restrict__ h,
    float* __restrict__ out)
{
    int n = blockIdx.x * blockDim.x + threadIdx.x;
    if (n >= N_NODES) return;
    const float* xr = x + n * 16;
    float xv[16];
    #pragma unroll
    for (int i = 0; i < 4; ++i) ((floatx4*)xv)[i] = ((const floatx4*)xr)[i];
    float mu = 0.f;
    #pragma unroll
    for (int i = 0; i < 16; ++i) mu += xv[i];
    mu *= (1.f / 16.f);
    float var = 0.f;
    #pragma unroll
    for (int i = 0; i < 16; ++i) { float d = xv[i] - mu; var += d * d; }
    var *= (1.f / 16.f);
    float rs = rsqrtf(var + 1e-5f);
    float hv[16];
    #pragma unroll
    for (int i = 0; i < 16; ++i) {
        float t = (xv[i] - mu) * rs * gamma[i] + beta[i];
        hv[i] = t > 0.f ? t : 0.f;
    }
    float* hr = h + n * 16;
    #pragma unroll
    for (int i = 0; i < 4; ++i) ((floatx4*)hr)[i] = ((floatx4*)hv)[i];
    float ov[16];
    #pragma unroll
    for (int o = 0; o < 16; ++o) ov[o] = bias[o];
    #pragma unroll
    for (int i = 0; i < 16; ++i) {
        float hi = hv[i];
        #pragma unroll
        for (int o = 0; o < 16; ++o) ov[o] += hi * root[i * 16 + o];
    }
    float* orow = out + n * 16;
    #pragma unroll
    for (int i = 0; i < 4; ++i) ((floatx4*)orow)[i] = ((floatx4*)ov)[i];
}

// Kernel B: counting-scatter — build per-destination edge lists.
// 800k int atomics (vs 12.8M fp32 before).
__global__ __launch_bounds__(256) void scatter_kernel(
    const int* __restrict__ eidx, int* __restrict__ cnt, int* __restrict__ slots)
{
    int e = blockIdx.x * blockDim.x + threadIdx.x;
    if (e >= E_EDGES) return;
    int dst = eidx[E_EDGES + e];
    int pos = atomicAdd(cnt + dst, 1);
    if (pos < CAP) slots[dst * CAP + pos] = e;
}

// Kernel C: one wave per node. MFMA the node's incoming edges 16 at a time
// (same rank-1 factorization: z[e, t*16+i] = ea[e,t]*h[src,i], K=160 padded),
// accumulate across tiles in registers, row-sum the C tile, single exclusive
// non-atomic RMW of out[n].
__global__ __launch_bounds__(256) void gather_kernel(
    const int* __restrict__ eidx, const float* __restrict__ ea,
    const float* __restrict__ w_edge, const float* __restrict__ b_edge,
    const float* __restrict__ h, const int* __restrict__ cnt,
    const int* __restrict__ slots, float* __restrict__ out)
{
    const int lane = threadIdx.x & 63;
    const int wid  = threadIdx.x >> 6;
    const int m = lane & 15;   // edge-in-tile (A row) / output col (B, C/D)
    const int q = lane >> 4;   // quad

    const int n = blockIdx.x * 4 + wid;   // node this wave owns
    if (n >= N_NODES) return;

    // B fragments: lane holds B[32c + 8q + j][m]  (loop-invariant)
    short8 bfrag[5];
    #pragma unroll
    for (int c = 0; c < 5; ++c) {
        short8 f;
        #pragma unroll
        for (int j = 0; j < 8; ++j) {
            int k = 32 * c + 8 * q + j;
            float v = 0.f;
            if (k < 128)      v = w_edge[(k >> 4) * 256 + (k & 15) * 16 + m];
            else if (k < 144) v = b_edge[(k - 128) * 16 + m];
            f[j] = f2bf(v);
        }
        bfrag[c] = f;
    }

    int deg = cnt[n];
    if (deg > CAP) deg = CAP;
    const int base = n * CAP;

    floatx4 acc = {0.f, 0.f, 0.f, 0.f};
    const int hi_t = q >> 1;

    for (int s0 = 0; s0 < deg; s0 += 16) {
        const int s = s0 + m;
        const bool valid = s < deg;
        floatx4 ea0 = {0,0,0,0}, ea1 = {0,0,0,0};
        floatx4 h0  = {0,0,0,0}, h1  = {0,0,0,0};
        if (valid) {
            const int e   = slots[base + s];
            const int src = eidx[e];
            const floatx4* er = (const floatx4*)(ea + (size_t)e * 8);
            ea0 = er[0];
            ea1 = er[1];
            const float* hr = h + src * 16 + 8 * (q & 1);
            h0 = ((const floatx4*)hr)[0];
            h1 = ((const floatx4*)hr)[1];
        }
        float hh[8] = {h0.x, h0.y, h0.z, h0.w, h1.x, h1.y, h1.z, h1.w};

        #pragma unroll
        for (int c = 0; c < 4; ++c) {
            float t_even, t_odd;
            if (c == 0)      { t_even = ea0.x; t_odd = ea0.y; }
            else if (c == 1) { t_even = ea0.z; t_odd = ea0.w; }
            else if (c == 2) { t_even = ea1.x; t_odd = ea1.y; }
            else             { t_even = ea1.z; t_odd = ea1.w; }
            float sc = hi_t ? t_odd : t_even;
            short8 af;
            #pragma unroll
            for (int j = 0; j < 8; ++j) af[j] = f2bf(sc * hh[j]);
            acc = __builtin_amdgcn_mfma_f32_16x16x32_bf16(af, bfrag[c], acc, 0, 0, 0);
        }
        // chunk 4: bias rows, z = h[i] for q<2 (zeros for invalid lanes since hh=0)
        short8 af4;
        #pragma unroll
        for (int j = 0; j < 8; ++j) af4[j] = (q < 2) ? f2bf(hh[j]) : (short)0;
        acc = __builtin_amdgcn_mfma_f32_16x16x32_bf16(af4, bfrag[4], acc, 0, 0, 0);
    }

    // Row-sum the 16x16 C tile: lane (q,m) holds rows 4q..4q+3 of col m.
    float colsum = acc[0] + acc[1] + acc[2] + acc[3];
    colsum += __shfl_xor(colsum, 16, 64);
    colsum += __shfl_xor(colsum, 32, 64);

    if (q == 0) {
        // exclusive owner of node n: plain RMW (out = bias + h@root already there)
        out[n * 16 + m] += colsum;
    }
}

extern "C" void kernel_launch(void* const* d_in, const int* in_sizes, int n_in,
                              void* d_out, int out_size, void* d_ws, size_t ws_size,
                              hipStream_t stream) {
    const float* x        = (const float*)d_in[0];
    const int*   eidx     = (const int*)d_in[1];
    const float* ea       = (const float*)d_in[2];
    const float* ln_gamma = (const float*)d_in[3];
    const float* ln_beta  = (const float*)d_in[4];
    const float* w_edge   = (const float*)d_in[5];
    const float* b_edge   = (const float*)d_in[6];
    const float* root     = (const float*)d_in[7];
    const float* bias     = (const float*)d_in[8];
    float* out = (float*)d_out;

    // workspace layout: h [3.2 MB] | cnt [0.2 MB] | slots [12.8 MB]
    char* ws = (char*)d_ws;
    float* h    = (float*)ws;                                   // N*16 f32
    int*   cnt  = (int*)(ws + (size_t)N_NODES * 16 * 4);        // N int
    int*   slots = (int*)(ws + (size_t)N_NODES * 16 * 4 + (size_t)N_NODES * 4); // N*CAP int

    hipMemsetAsync(cnt, 0, (size_t)N_NODES * 4, stream);

    node_kernel<<<(N_NODES + 255) / 256, 256, 0, stream>>>(
        x, ln_gamma, ln_beta, root, bias, h, out);
    scatter_kernel<<<(E_EDGES + 255) / 256, 256, 0, stream>>>(eidx, cnt, slots);
    gather_kernel<<<(N_NODES + 3) / 4, 256, 0, stream>>>(
        eidx, ea, w_edge, b_edge, h, cnt, slots, out);
}

// Round 4
// 140.063 us; speedup vs baseline: 1.3754x; 1.3754x over previous
//
#include <hip/hip_runtime.h>
#include <hip/hip_fp16.h>

#define N_NODES 50000
#define E_EDGES 800000
#define NTILES  (E_EDGES / 16)   // 50000 exact

typedef __attribute__((ext_vector_type(8))) short short8;
typedef __attribute__((ext_vector_type(4))) float floatx4;

// float -> bf16 bits, round-to-nearest-even
__device__ __forceinline__ short f2bf(float x) {
    union { float f; unsigned u; } v; v.f = x;
    unsigned r = v.u + 0x7FFFu + ((v.u >> 16) & 1u);
    return (short)(r >> 16);
}

// Kernel A: per-node LayerNorm+ReLU -> h; out = bias + h @ root
__global__ __launch_bounds__(256) void node_kernel(
    const float* __restrict__ x, const float* __restrict__ gamma,
    const float* __restrict__ beta, const float* __restrict__ root,
    const float* __restrict__ bias, float* __restrict__ h,
    float* __restrict__ out)
{
    int n = blockIdx.x * blockDim.x + threadIdx.x;
    if (n >= N_NODES) return;
    const float* xr = x + n * 16;
    float xv[16];
    #pragma unroll
    for (int i = 0; i < 4; ++i) ((floatx4*)xv)[i] = ((const floatx4*)xr)[i];
    float mu = 0.f;
    #pragma unroll
    for (int i = 0; i < 16; ++i) mu += xv[i];
    mu *= (1.f / 16.f);
    float var = 0.f;
    #pragma unroll
    for (int i = 0; i < 16; ++i) { float d = xv[i] - mu; var += d * d; }
    var *= (1.f / 16.f);
    float rs = rsqrtf(var + 1e-5f);
    float hv[16];
    #pragma unroll
    for (int i = 0; i < 16; ++i) {
        float t = (xv[i] - mu) * rs * gamma[i] + beta[i];
        hv[i] = t > 0.f ? t : 0.f;
    }
    float* hr = h + n * 16;
    #pragma unroll
    for (int i = 0; i < 4; ++i) ((floatx4*)hr)[i] = ((floatx4*)hv)[i];
    float ov[16];
    #pragma unroll
    for (int o = 0; o < 16; ++o) ov[o] = bias[o];
    #pragma unroll
    for (int i = 0; i < 16; ++i) {
        float hi = hv[i];
        #pragma unroll
        for (int o = 0; o < 16; ++o) ov[o] += hi * root[i * 16 + o];
    }
    float* orow = out + n * 16;
    #pragma unroll
    for (int i = 0; i < 4; ++i) ((floatx4*)orow)[i] = ((floatx4*)ov)[i];
}

// Kernel B: per-wave tile of 16 edges (R2 structure: streaming-friendly
// FETCH). Epilogue: packed-f16 atomics (2 cols/op) into f16 agg buffer —
// 8 ops/edge instead of 16 fp32 atomics. Atomic path is L2-access-slot
// bound, so halving op count should halve epilogue time.
__global__ __launch_bounds__(256) void edge_kernel(
    const int* __restrict__ eidx, const float* __restrict__ ea,
    const float* __restrict__ w_edge, const float* __restrict__ b_edge,
    const float* __restrict__ h, __half* __restrict__ agg)
{
    const int lane = threadIdx.x & 63;
    const int wid  = threadIdx.x >> 6;
    const int m = lane & 15;   // edge-in-tile for A; output col for C/D and B
    const int q = lane >> 4;   // quad

    // B fragments: lane holds B[32c + 8q + j][m]  (loop-invariant)
    short8 bfrag[5];
    #pragma unroll
    for (int c = 0; c < 5; ++c) {
        short8 f;
        #pragma unroll
        for (int j = 0; j < 8; ++j) {
            int k = 32 * c + 8 * q + j;
            float v = 0.f;
            if (k < 128)      v = w_edge[(k >> 4) * 256 + (k & 15) * 16 + m];
            else if (k < 144) v = b_edge[(k - 128) * 16 + m];
            f[j] = f2bf(v);
        }
        bfrag[c] = f;
    }

    const int nw = (gridDim.x * blockDim.x) >> 6;
    for (int tile = blockIdx.x * (blockDim.x >> 6) + wid; tile < NTILES; tile += nw) {
        const int e   = tile * 16 + m;
        const int src = eidx[e];
        const int dst = eidx[E_EDGES + e];

        const float* er = ea + (size_t)e * 8;
        floatx4 ea0 = ((const floatx4*)er)[0];
        floatx4 ea1 = ((const floatx4*)er)[1];

        const float* hr = h + src * 16 + 8 * (q & 1);
        floatx4 h0 = ((const floatx4*)hr)[0];
        floatx4 h1 = ((const floatx4*)hr)[1];
        float hh[8] = {h0.x, h0.y, h0.z, h0.w, h1.x, h1.y, h1.z, h1.w};

        floatx4 acc = {0.f, 0.f, 0.f, 0.f};
        const int hi_t = q >> 1;
        #pragma unroll
        for (int c = 0; c < 4; ++c) {
            float t_even, t_odd;
            if (c == 0)      { t_even = ea0.x; t_odd = ea0.y; }
            else if (c == 1) { t_even = ea0.z; t_odd = ea0.w; }
            else if (c == 2) { t_even = ea1.x; t_odd = ea1.y; }
            else             { t_even = ea1.z; t_odd = ea1.w; }
            float s = hi_t ? t_odd : t_even;
            short8 af;
            #pragma unroll
            for (int j = 0; j < 8; ++j) af[j] = f2bf(s * hh[j]);
            acc = __builtin_amdgcn_mfma_f32_16x16x32_bf16(af, bfrag[c], acc, 0, 0, 0);
        }
        short8 af4;
        #pragma unroll
        for (int j = 0; j < 8; ++j) af4[j] = (q < 2) ? f2bf(hh[j]) : (short)0;
        acc = __builtin_amdgcn_mfma_f32_16x16x32_bf16(af4, bfrag[4], acc, 0, 0, 0);

        // C/D layout: col = m, row = 4q + r (edge index in tile).
        // Pair adjacent cols across lanes; even-m lanes issue pk_add_f16.
        #pragma unroll
        for (int r = 0; r < 4; ++r) {
            float v  = acc[r];
            float vn = __shfl_xor(v, 1, 64);       // partner column's value
            int   dr = __shfl(dst, 4 * q + r, 64); // dst of row 4q+r
            if (!(m & 1)) {
                __half2 hv;
                hv.x = __float2half(v);
                hv.y = __float2half(vn);
                unsafeAtomicAdd((__half2*)(agg + (size_t)dr * 16 + m), hv);
            }
        }
    }
}

// Kernel D: out += float(agg)   (out already holds bias + h@root)
__global__ __launch_bounds__(256) void finalize_kernel(
    const __half* __restrict__ agg, float* __restrict__ out)
{
    int t = blockIdx.x * blockDim.x + threadIdx.x;   // one __half2 per thread
    if (t >= N_NODES * 8) return;
    __half2 a = ((const __half2*)agg)[t];
    float2* op = (float2*)out + t;
    float2 o = *op;
    o.x += __half2float(a.x);
    o.y += __half2float(a.y);
    *op = o;
}

extern "C" void kernel_launch(void* const* d_in, const int* in_sizes, int n_in,
                              void* d_out, int out_size, void* d_ws, size_t ws_size,
                              hipStream_t stream) {
    const float* x        = (const float*)d_in[0];
    const int*   eidx     = (const int*)d_in[1];
    const float* ea       = (const float*)d_in[2];
    const float* ln_gamma = (const float*)d_in[3];
    const float* ln_beta  = (const float*)d_in[4];
    const float* w_edge   = (const float*)d_in[5];
    const float* b_edge   = (const float*)d_in[6];
    const float* root     = (const float*)d_in[7];
    const float* bias     = (const float*)d_in[8];
    float* out = (float*)d_out;

    // workspace: h [N*16 f32 = 3.2 MB] | agg [N*16 f16 = 1.6 MB]
    char* ws = (char*)d_ws;
    float*  h   = (float*)ws;
    __half* agg = (__half*)(ws + (size_t)N_NODES * 16 * 4);

    hipMemsetAsync(agg, 0, (size_t)N_NODES * 16 * 2, stream);

    node_kernel<<<(N_NODES + 255) / 256, 256, 0, stream>>>(
        x, ln_gamma, ln_beta, root, bias, h, out);
    edge_kernel<<<2048, 256, 0, stream>>>(eidx, ea, w_edge, b_edge, h, agg);
    finalize_kernel<<<(N_NODES * 8 + 255) / 256, 256, 0, stream>>>(agg, out);
}

// Round 5
// 131.155 us; speedup vs baseline: 1.4689x; 1.0679x over previous
//
#include <hip/hip_runtime.h>

#define N_NODES 50000
#define E_EDGES 800000
#define NTILES  (E_EDGES / 16)   // 50000 exact

typedef __attribute__((ext_vector_type(8))) short short8;
typedef __attribute__((ext_vector_type(4))) float floatx4;

// float -> bf16 bits, round-to-nearest-even (used in prep only)
__device__ __forceinline__ short f2bf(float x) {
    union { float f; unsigned u; } v; v.f = x;
    unsigned r = v.u + 0x7FFFu + ((v.u >> 16) & 1u);
    return (short)(r >> 16);
}

// pack bf16x2 (RTZ) from two floats via v_perm_b32: 1 VALU per pair
__device__ __forceinline__ unsigned pk_bf16(float lo, float hi) {
    union { float f; unsigned u; } a, b; a.f = lo; b.f = hi;
    return __builtin_amdgcn_perm(b.u, a.u, 0x07060302u);
}

// Kernel A: per-node LayerNorm+ReLU -> h; out = bias + h @ root
__global__ __launch_bounds__(256) void node_kernel(
    const float* __restrict__ x, const float* __restrict__ gamma,
    const float* __restrict__ beta, const float* __restrict__ root,
    const float* __restrict__ bias, float* __restrict__ h,
    float* __restrict__ out)
{
    int n = blockIdx.x * blockDim.x + threadIdx.x;
    if (n >= N_NODES) return;
    const float* xr = x + n * 16;
    float xv[16];
    #pragma unroll
    for (int i = 0; i < 4; ++i) ((floatx4*)xv)[i] = ((const floatx4*)xr)[i];
    float mu = 0.f;
    #pragma unroll
    for (int i = 0; i < 16; ++i) mu += xv[i];
    mu *= (1.f / 16.f);
    float var = 0.f;
    #pragma unroll
    for (int i = 0; i < 16; ++i) { float d = xv[i] - mu; var += d * d; }
    var *= (1.f / 16.f);
    float rs = rsqrtf(var + 1e-5f);
    float hv[16];
    #pragma unroll
    for (int i = 0; i < 16; ++i) {
        float t = (xv[i] - mu) * rs * gamma[i] + beta[i];
        hv[i] = t > 0.f ? t : 0.f;
    }
    float* hr = h + n * 16;
    #pragma unroll
    for (int i = 0; i < 4; ++i) ((floatx4*)hr)[i] = ((floatx4*)hv)[i];
    float ov[16];
    #pragma unroll
    for (int o = 0; o < 16; ++o) ov[o] = bias[o];
    #pragma unroll
    for (int i = 0; i < 16; ++i) {
        float hi = hv[i];
        #pragma unroll
        for (int o = 0; o < 16; ++o) ov[o] += hi * root[i * 16 + o];
    }
    float* orow = out + n * 16;
    #pragma unroll
    for (int i = 0; i < 4; ++i) ((floatx4*)orow)[i] = ((floatx4*)ov)[i];
}

// Kernel W: W2t[m][k] = bf16(W2[k][m]), [16][160] bf16 = 5 KB.
// W2[k][o]: k<128 -> w_edge[(k>>4)*256 + (k&15)*16 + o]; 128..143 -> b_edge; else 0.
__global__ __launch_bounds__(256) void prep_kernel(
    const float* __restrict__ w_edge, const float* __restrict__ b_edge,
    short* __restrict__ w2t)
{
    int t = blockIdx.x * blockDim.x + threadIdx.x;
    if (t >= 16 * 160) return;
    int m = t / 160, k = t % 160;
    float v = 0.f;
    if (k < 128)      v = w_edge[(k >> 4) * 256 + (k & 15) * 16 + m];
    else if (k < 144) v = b_edge[(k - 128) * 16 + m];
    w2t[m * 160 + k] = f2bf(v);
}

// Kernel B: ONE wave per tile of 16 edges — no loop; wave churn hides the
// gather chain. B-frags: 5 x 16B vector loads from W2t. A-frags packed with
// v_perm (RTZ). Epilogue: 4 fp32 atomic instrs into out.
__global__ __launch_bounds__(256) void edge_kernel(
    const int* __restrict__ eidx, const float* __restrict__ ea,
    const short* __restrict__ w2t, const float* __restrict__ h,
    float* __restrict__ out)
{
    const int lane = threadIdx.x & 63;
    const int wid  = threadIdx.x >> 6;
    const int m = lane & 15;   // edge-in-tile for A; output col for C/D and B
    const int q = lane >> 4;   // quad

    const int tile = blockIdx.x * 4 + wid;
    if (tile >= NTILES) return;

    const int e   = tile * 16 + m;
    const int src = eidx[e];
    const int dst = eidx[E_EDGES + e];

    // B fragments: lane needs W2[32c+8q+j][m] = w2t[m*160 + 32c+8q + j], j=0..7
    // contiguous -> one 16B load per chunk.
    const short* wp = w2t + m * 160 + 8 * q;
    short8 bfrag[5];
    #pragma unroll
    for (int c = 0; c < 5; ++c)
        bfrag[c] = *(const short8*)(wp + 32 * c);

    const float* er = ea + (size_t)e * 8;
    floatx4 ea0 = ((const floatx4*)er)[0];
    floatx4 ea1 = ((const floatx4*)er)[1];

    const float* hr = h + src * 16 + 8 * (q & 1);
    floatx4 h0 = ((const floatx4*)hr)[0];
    floatx4 h1 = ((const floatx4*)hr)[1];
    float hh[8] = {h0.x, h0.y, h0.z, h0.w, h1.x, h1.y, h1.z, h1.w};

    floatx4 acc = {0.f, 0.f, 0.f, 0.f};
    const int hi_t = q >> 1;
    #pragma unroll
    for (int c = 0; c < 4; ++c) {
        float t_even, t_odd;
        if (c == 0)      { t_even = ea0.x; t_odd = ea0.y; }
        else if (c == 1) { t_even = ea0.z; t_odd = ea0.w; }
        else if (c == 2) { t_even = ea1.x; t_odd = ea1.y; }
        else             { t_even = ea1.z; t_odd = ea1.w; }
        float s = hi_t ? t_odd : t_even;
        union { short8 s8; unsigned u[4]; } af;
        #pragma unroll
        for (int p = 0; p < 4; ++p)
            af.u[p] = pk_bf16(s * hh[2 * p], s * hh[2 * p + 1]);
        acc = __builtin_amdgcn_mfma_f32_16x16x32_bf16(af.s8, bfrag[c], acc, 0, 0, 0);
    }
    // chunk 4: z = h[i] for q<2, 0 otherwise (mask the packed words)
    {
        const unsigned msk = (q < 2) ? 0xFFFFFFFFu : 0u;
        union { short8 s8; unsigned u[4]; } af;
        #pragma unroll
        for (int p = 0; p < 4; ++p)
            af.u[p] = pk_bf16(hh[2 * p], hh[2 * p + 1]) & msk;
        acc = __builtin_amdgcn_mfma_f32_16x16x32_bf16(af.s8, bfrag[4], acc, 0, 0, 0);
    }

    // C/D layout: col = m, row = 4q + r (edge index in tile)
    #pragma unroll
    for (int r = 0; r < 4; ++r) {
        int dr = __shfl(dst, 4 * q + r, 64);
        atomicAdd(out + (size_t)dr * 16 + m, acc[r]);
    }
}

extern "C" void kernel_launch(void* const* d_in, const int* in_sizes, int n_in,
                              void* d_out, int out_size, void* d_ws, size_t ws_size,
                              hipStream_t stream) {
    const float* x        = (const float*)d_in[0];
    const int*   eidx     = (const int*)d_in[1];
    const float* ea       = (const float*)d_in[2];
    const float* ln_gamma = (const float*)d_in[3];
    const float* ln_beta  = (const float*)d_in[4];
    const float* w_edge   = (const float*)d_in[5];
    const float* b_edge   = (const float*)d_in[6];
    const float* root     = (const float*)d_in[7];
    const float* bias     = (const float*)d_in[8];
    float* out = (float*)d_out;

    // workspace: h [N*16 f32 = 3.2 MB] | w2t [16*160 bf16 = 5 KB]
    char* ws = (char*)d_ws;
    float* h   = (float*)ws;
    short* w2t = (short*)(ws + (size_t)N_NODES * 16 * 4);

    prep_kernel<<<10, 256, 0, stream>>>(w_edge, b_edge, w2t);
    node_kernel<<<(N_NODES + 255) / 256, 256, 0, stream>>>(
        x, ln_gamma, ln_beta, root, bias, h, out);
    // one wave per 16-edge tile: 50000 waves, 12500 blocks
    edge_kernel<<<(NTILES + 3) / 4, 256, 0, stream>>>(eidx, ea, w2t, h, out);
}